// Round 19
// baseline (351.508 us; speedup 1.0000x reference)
//
#include <hip/hip_runtime.h>
#include <hip/hip_bf16.h>

typedef __hip_bfloat16 bf16;
typedef __attribute__((ext_vector_type(8))) short short8;
typedef __attribute__((ext_vector_type(4))) short s16x4;
typedef __attribute__((ext_vector_type(4))) float f32x4;

__device__ __forceinline__ bf16 f2b(float f) { return __float2bfloat16(f); }
__device__ __forceinline__ short bfbits(float f) {
  union { float f; unsigned u; } x; x.f = f;
  unsigned r = x.u + 0x7fff + ((x.u >> 16) & 1);  // RNE
  return (short)(r >> 16);
}
// tanh(x) = sign(x) * (1-t)/(1+t), t = e^{-2|x|}  — ~8 VALU ops, err ~1e-6
__device__ __forceinline__ float tanh_fast(float x) {
  float t = __expf(-2.f * fabsf(x));
  float r = (1.f - t) * __builtin_amdgcn_rcpf(1.f + t);
  return copysignf(r, x);
}

#define GLOAD_LDS16(gp, lp) __builtin_amdgcn_global_load_lds( \
    (const __attribute__((address_space(1))) void*)(gp), \
    (__attribute__((address_space(3))) void*)(lp), 16, 0, 0)
#define SBAR() __builtin_amdgcn_s_barrier()
#define WAITV(n) do { asm volatile("s_waitcnt vmcnt(" #n ")" ::: "memory"); \
                      __builtin_amdgcn_sched_barrier(0); } while (0)
#define LGKM0() do { asm volatile("s_waitcnt lgkmcnt(0)" ::: "memory"); \
                     __builtin_amdgcn_sched_barrier(0); } while (0)

// ---------------- prep: bf16 weight layouts (coalesced transpose) ----------
__global__ __launch_bounds__(256) void prep(
    const float* __restrict__ W2, const float* __restrict__ Wf2,
    const float* __restrict__ W1, const float* __restrict__ Wff,
    bf16* __restrict__ W2bf, bf16* __restrict__ W2Tbf,
    bf16* __restrict__ Wf2bf, bf16* __restrict__ W1n,
    bf16* __restrict__ Wffn)
{
  __shared__ float T[32][33];
  const int tid = threadIdx.x, bx = blockIdx.x;
  const int tx = bx & 31, ty = bx >> 5;
  const int r = tid >> 3, c4 = (tid & 7) * 4;
  const long ibase = (long)(ty * 32 + r) * 1024 + tx * 32 + c4;

  f32x4 v = *(const f32x4*)(W2 + ibase);
  f32x4 vf = *(const f32x4*)(Wf2 + ibase);
  s16x4 sv, sf;
  #pragma unroll
  for (int j = 0; j < 4; ++j) {
    sv[j] = bfbits(v[j]); sf[j] = bfbits(vf[j]);
    T[r][c4 + j] = v[j];
  }
  *(s16x4*)(W2bf + ibase) = sv;
  *(s16x4*)(Wf2bf + ibase) = sf;
  __syncthreads();
  const int oc = tid >> 3, or4 = (tid & 7) * 4;
  s16x4 st;
  #pragma unroll
  for (int j = 0; j < 4; ++j) st[j] = bfbits(T[or4 + j][oc]);
  *(s16x4*)(W2Tbf + (long)(tx * 32 + oc) * 1024 + ty * 32 + or4) = st;

  if (bx < 32) {  // W1n (16x1024, transpose of W1) + Wffn (straight)
    #pragma unroll
    for (int rep = 0; rep < 2; ++rep) {
      int i = bx * 512 + rep * 256 + tid;
      int rr = i >> 10, cc = i & 1023;
      W1n[i] = f2b(W1[cc * 16 + rr]);
      Wffn[i] = f2b(Wff[i]);
    }
  }
}

// ---------------- K1: h1 = tanh(z@W1^T+b1); f1 = [z,u]@Wf1^T+bf1 -----------
__global__ __launch_bounds__(256) void k1(
    const float* __restrict__ z, const float* __restrict__ W1,
    const float* __restrict__ b1, const float* __restrict__ Wp,
    const float* __restrict__ bp, const float* __restrict__ Wf1,
    const float* __restrict__ bf1v,
    bf16* __restrict__ h1, bf16* __restrict__ f1out, long grow0)
{
  __shared__ float zs[32][16];
  __shared__ float us[32][4];
  const int tid = threadIdx.x;
  const long r0 = (long)blockIdx.x * 32;
  for (int i = tid; i < 512; i += 256) {
    int r = i >> 4, c = i & 15;
    zs[r][c] = z[(grow0 + r0 + r) * 16 + c];
  }
  __syncthreads();
  if (tid < 128) {
    int r = tid >> 2, a = tid & 3;
    float acc = bp[a];
    #pragma unroll
    for (int k = 0; k < 16; ++k) acc = fmaf(zs[r][k], Wp[a * 16 + k], acc);
    us[r][a] = tanh_fast(acc);
  }
  __syncthreads();
  #pragma unroll
  for (int jj = 0; jj < 4; ++jj) {
    const int c = tid + jj * 256;
    {  // h1
      float w[16];
      #pragma unroll
      for (int k = 0; k < 16; ++k) w[k] = W1[c * 16 + k];
      const float bc = b1[c];
      for (int r = 0; r < 32; ++r) {
        float a = bc;
        #pragma unroll
        for (int k = 0; k < 16; ++k) a = fmaf(zs[r][k], w[k], a);
        h1[(r0 + r) * 1024 + c] = f2b(tanh_fast(a));
      }
    }
    {  // f1
      float wf[20];
      #pragma unroll
      for (int k = 0; k < 20; ++k) wf[k] = Wf1[c * 20 + k];
      const float bfc = bf1v[c];
      for (int r = 0; r < 32; ++r) {
        float f = bfc;
        #pragma unroll
        for (int k = 0; k < 16; ++k) f = fmaf(zs[r][k], wf[k], f);
        #pragma unroll
        for (int a = 0; a < 4; ++a) f = fmaf(us[r][a], wf[16 + a], f);
        f1out[(r0 + r) * 1024 + c] = f2b(f);
      }
    }
  }
}

// ---------------- MFMA GEMM 256x256, 8 waves, BK=64, 4-phase counted ------
// m201-style schedule on the R18 frame. LDS per tile: A,B each as 2 k-slabs
// [256 rows][32 k] (slab = proven BK=32 layout -> 64-B row stride, XOR
// swizzle conflict-free). 2 bufs x (A 32K + B 32K) = 128 KB.
// Staging is K-HALF granular: half h of a tile = {A j0, A j1, B j0, B j1}
// = 4 gloads (each 512 thr x 16 B = rows j*128..+127 of slab h).
// Per K-step: 4 phases (kc, m-half): {ds_read quadrant frags || 2 prefetch
// gloads -> SBAR -> lgkmcnt(0) -> setprio(1) -> 16 MFMA -> setprio(0) ->
// [WAITV(4) at phases 1,3] -> SBAR}. Ledger (steady state): entry P0
// in-flight = kc1(kt) [4]; P0,P1 push kc0(kt+1); P1 WAITV(4) retires
// kc1(kt) before P2 reads it; P2,P3 push kc1(kt+1); P3 WAITV(4) retires
// kc0(kt+1) before next P0 reads it. Never drains to 0 until epilogue
// (kt=15: WAITV(0) at P1). Writes go to buf c^1 while reads touch buf c.
// EPI 0: x=a2. h2=tanh(x+b2); s1=1-h2^2; O2=gb=s1*Wh[c];
//        f=O1[idx] (=f1 precomputed); O1=g1f=tanh(f)+f*s1 IN PLACE.
// EPI 1/2: g-tile -> Ot[256][136] in two column-half phases, project @Wn^T,
//          write Pp partials (per col-block).
template<int EPI>
__global__ __launch_bounds__(512, 2) void gemm_k(
    const bf16* __restrict__ A, const bf16* __restrict__ Bp,
    const float* __restrict__ bias, const float* __restrict__ Whv,
    const bf16* __restrict__ h1,
    bf16* O1, bf16* __restrict__ O2,   // O1 NOT restrict: in-place f1->g1f
    const bf16* __restrict__ Wn, float* __restrict__ Pp, int ckRows)
{
  __shared__ __align__(16) char smem[131072];  // A[2 tiles] @0, B[2] @65536
  const int tid = threadIdx.x;
  const int lane = tid & 63, wid = tid >> 6;
  const int wr = wid >> 2, wc = wid & 3;
  const int fr = lane & 15, kg = lane >> 4;
  const long row0 = (long)blockIdx.x * 256;
  const int col0 = blockIdx.y * 256;

  // staging thread map (per gload): row = tid>>2 within 128-row half,
  // dest chunk tid&3; source k-chunk pre-swizzled: (tid&3)^((tid>>3)&3)
  const int sk0 = ((tid & 3) ^ ((tid >> 3) & 3)) * 8;
  const int swr = (fr >> 1) & 3;                       // read-side XOR term

  const bf16* gA0 = A + (row0 + (tid >> 2)) * 1024 + sk0;
  const bf16* gB0 = Bp + ((long)col0 + (tid >> 2)) * 1024 + sk0;
  // within-slab read offsets (elements): row*32 + (kg^swr)*8; +m(n)*512
  const int rdA = (wr * 128 + fr) * 32 + (kg ^ swr) * 8;
  const int rdB = (wc * 64 + fr) * 32 + (kg ^ swr) * 8;

  bf16* const Ae = (bf16*)smem;            // A tiles: c*16384 + kc*8192
  bf16* const Be = (bf16*)smem + 32768;    // B tiles: c*16384 + kc*8192

  f32x4 acc[8][4] = {};

  auto stageA = [&](int c1, int k0, int h) {
    bf16* d = Ae + c1 * 16384 + h * 8192;
    GLOAD_LDS16(gA0 + k0 + h * 32, d + tid * 8);                   // rows 0-127
    GLOAD_LDS16(gA0 + 128 * 1024 + k0 + h * 32, d + 4096 + tid * 8); // 128-255
  };
  auto stageB = [&](int c1, int k0, int h) {
    bf16* d = Be + c1 * 16384 + h * 8192;
    GLOAD_LDS16(gB0 + k0 + h * 32, d + tid * 8);
    GLOAD_LDS16(gB0 + 128 * 1024 + k0 + h * 32, d + 4096 + tid * 8);
  };

  // prologue: tile 0 -> buf 0, canonical order A-h0,B-h0,A-h1,B-h1
  stageA(0, 0, 0); stageB(0, 0, 0); stageA(0, 0, 1); stageB(0, 0, 1);
  WAITV(4);   // kc0 of tile 0 resident; kc1 (4 loads) still in flight
  SBAR();

  #pragma unroll 2
  for (int kt = 0; kt < 16; ++kt) {
    const int c = kt & 1;                  // static under unroll-2
    const int c1 = c ^ 1;
    const int k0 = (kt + 1) * 64;
    const bf16* as = Ae + c * 16384;
    const bf16* bs = Be + c * 16384;
    short8 af[4], bfr[4];

    // ---- phase 0: kc0, m=0..3 (+ all B kc0); prefetch A-h0 of kt+1
    #pragma unroll
    for (int m = 0; m < 4; ++m)
      af[m] = *(const short8*)(as + rdA + m * 512);
    #pragma unroll
    for (int n = 0; n < 4; ++n)
      bfr[n] = *(const short8*)(bs + rdB + n * 512);
    if (kt < 15) stageA(c1, k0, 0);
    SBAR(); LGKM0();
    __builtin_amdgcn_s_setprio(1);
    #pragma unroll
    for (int m = 0; m < 4; ++m)
      #pragma unroll
      for (int n = 0; n < 4; ++n)
        acc[m][n] = __builtin_amdgcn_mfma_f32_16x16x32_bf16(af[m], bfr[n], acc[m][n], 0, 0, 0);
    __builtin_amdgcn_s_setprio(0);
    SBAR();

    // ---- phase 1: kc0, m=4..7; prefetch B-h0 of kt+1; WAITV retires kc1(kt)
    #pragma unroll
    for (int m = 0; m < 4; ++m)
      af[m] = *(const short8*)(as + rdA + (m + 4) * 512);
    if (kt < 15) stageB(c1, k0, 0);
    SBAR(); LGKM0();
    __builtin_amdgcn_s_setprio(1);
    #pragma unroll
    for (int m = 0; m < 4; ++m)
      #pragma unroll
      for (int n = 0; n < 4; ++n)
        acc[m + 4][n] = __builtin_amdgcn_mfma_f32_16x16x32_bf16(af[m], bfr[n], acc[m + 4][n], 0, 0, 0);
    __builtin_amdgcn_s_setprio(0);
    if (kt < 15) WAITV(4); else WAITV(0);
    SBAR();

    // ---- phase 2: kc1, m=0..3 (+ all B kc1); prefetch A-h1 of kt+1
    #pragma unroll
    for (int m = 0; m < 4; ++m)
      af[m] = *(const short8*)(as + 8192 + rdA + m * 512);
    #pragma unroll
    for (int n = 0; n < 4; ++n)
      bfr[n] = *(const short8*)(bs + 8192 + rdB + n * 512);
    if (kt < 15) stageA(c1, k0, 1);
    SBAR(); LGKM0();
    __builtin_amdgcn_s_setprio(1);
    #pragma unroll
    for (int m = 0; m < 4; ++m)
      #pragma unroll
      for (int n = 0; n < 4; ++n)
        acc[m][n] = __builtin_amdgcn_mfma_f32_16x16x32_bf16(af[m], bfr[n], acc[m][n], 0, 0, 0);
    __builtin_amdgcn_s_setprio(0);
    SBAR();

    // ---- phase 3: kc1, m=4..7; prefetch B-h1 of kt+1; WAITV retires kc0(kt+1)
    #pragma unroll
    for (int m = 0; m < 4; ++m)
      af[m] = *(const short8*)(as + 8192 + rdA + (m + 4) * 512);
    if (kt < 15) stageB(c1, k0, 1);
    SBAR(); LGKM0();
    __builtin_amdgcn_s_setprio(1);
    #pragma unroll
    for (int m = 0; m < 4; ++m)
      #pragma unroll
      for (int n = 0; n < 4; ++n)
        acc[m + 4][n] = __builtin_amdgcn_mfma_f32_16x16x32_bf16(af[m], bfr[n], acc[m + 4][n], 0, 0, 0);
    __builtin_amdgcn_s_setprio(0);
    if (kt < 15) WAITV(4); else WAITV(0);
    SBAR();
  }

  if (EPI == 0) {
    #pragma unroll
    for (int m = 0; m < 8; ++m) {
      const long gr0 = row0 + wr * 128 + m * 16 + kg * 4;
      #pragma unroll
      for (int n = 0; n < 4; ++n) {
        const int gc = col0 + wc * 64 + n * 16 + fr;
        const float b2c = bias[gc], whc = Whv[gc];
        f32x4 v = acc[m][n];
        #pragma unroll
        for (int j = 0; j < 4; ++j) {
          const long idx = (gr0 + j) * 1024 + gc;
          float h = tanh_fast(v[j] + b2c);
          float s1v = 1.f - h * h;
          float f = __bfloat162float(((const bf16*)O1)[idx]);  // f1 in place
          O2[idx] = f2b(s1v * whc);
          O1[idx] = f2b(tanh_fast(f) + f * s1v);
        }
      }
    }
  } else {
    bf16* Ot = (bf16*)smem;  // [256][136] bf16 — holds ONE column half
    f32x4 pacc[2] = {};
    #pragma unroll
    for (int ph = 0; ph < 2; ++ph) {
      if ((wc >> 1) == ph) {  // this wave's 64 cols live in half ph
        #pragma unroll
        for (int m = 0; m < 8; ++m) {
          const int rl0 = wr * 128 + m * 16 + kg * 4;
          const long gr0 = row0 + rl0;
          #pragma unroll
          for (int n = 0; n < 4; ++n) {
            const int cl = (wc & 1) * 64 + n * 16 + fr;       // 0..127
            const int gc = col0 + ph * 128 + cl;
            f32x4 v = acc[m][n];
            #pragma unroll
            for (int j = 0; j < 4; ++j) {
              const long idx = (gr0 + j) * 1024 + gc;
              float x = v[j], g;
              if (EPI == 1) {
                float hh = __bfloat162float(h1[idx]);
                g = x * (1.f - hh * hh);
              } else {
                float f = x + bias[gc];
                float hh = __bfloat162float(h1[idx]);
                g = tanh_fast(f) + f * (1.f - hh * hh);
              }
              Ot[(rl0 + j) * 136 + cl] = f2b(g);
            }
          }
        }
      }
      __syncthreads();  // half-tile staged
      #pragma unroll
      for (int sub = 0; sub < 2; ++sub) {
        const int rl0 = wid * 32 + sub * 16;
        #pragma unroll
        for (int ks = 0; ks < 4; ++ks) {
          short8 afrag = *(const short8*)(Ot + (rl0 + fr) * 136 + ks * 32 + kg * 8);
          short8 bfrag = *(const short8*)(Wn + fr * 1024 + col0 + ph * 128 + ks * 32 + kg * 8);
          pacc[sub] = __builtin_amdgcn_mfma_f32_16x16x32_bf16(afrag, bfrag, pacc[sub], 0, 0, 0);
        }
      }
      if (ph == 0) __syncthreads();  // reads done before half 1 overwrites
    }
    #pragma unroll
    for (int sub = 0; sub < 2; ++sub) {
      const int rl0 = wid * 32 + sub * 16;
      #pragma unroll
      for (int j = 0; j < 4; ++j)
        Pp[(((long)blockIdx.y) * ckRows + row0 + rl0 + kg * 4 + j) * 16 + fr] = pacc[sub][j];
    }
  }
}

// ---------------- k7: out = J*(sum_cb(Pp0+Pp1) + bff) ----------------------
__global__ __launch_bounds__(256) void k7(
    const float* __restrict__ Pp0, const float* __restrict__ Pp1,
    const float* __restrict__ bff, float* __restrict__ out,
    long grow0, int ckRows)
{
  int i = blockIdx.x * 256 + threadIdx.x;
  int r = i >> 4, j = i & 15, jp = (j + 8) & 15;
  float s = bff[jp];
  #pragma unroll
  for (int cb = 0; cb < 4; ++cb) {
    long o = ((long)cb * ckRows + r) * 16 + jp;
    s += Pp0[o] + Pp1[o];
  }
  out[(grow0 + r) * 16 + j] = (j < 8) ? s : -s;
}

// ---------------- host ----------------
extern "C" void kernel_launch(void* const* d_in, const int* in_sizes, int n_in,
                              void* d_out, int out_size, void* d_ws, size_t ws_size,
                              hipStream_t stream) {
  const float* z   = (const float*)d_in[1];
  const float* W1  = (const float*)d_in[2];
  const float* b1  = (const float*)d_in[3];
  const float* W2  = (const float*)d_in[4];
  const float* b2  = (const float*)d_in[5];
  const float* Wh  = (const float*)d_in[6];
  const float* Wf1 = (const float*)d_in[8];
  const float* bf1 = (const float*)d_in[9];
  const float* Wf2 = (const float*)d_in[10];
  const float* bf2 = (const float*)d_in[11];
  const float* Wff = (const float*)d_in[12];
  const float* bff = (const float*)d_in[13];
  const float* Wp  = (const float*)d_in[14];
  const float* bp  = (const float*)d_in[15];
  float* out = (float*)d_out;
  const int N = in_sizes[1] / 16;

  char* p = (char*)d_ws;
  auto alloc = [&](size_t bytes) {
    char* q = p; p += (bytes + 255) & ~(size_t)255; return q;
  };
  bf16* W2bf  = (bf16*)alloc(1024 * 1024 * 2);
  bf16* W2Tbf = (bf16*)alloc(1024 * 1024 * 2);
  bf16* Wf2bf = (bf16*)alloc(1024 * 1024 * 2);
  bf16* W1n   = (bf16*)alloc(16 * 1024 * 2);
  bf16* Wffn  = (bf16*)alloc(16 * 1024 * 2);
  size_t wbytes = (size_t)(p - (char*)d_ws);

  int CK = N;  // chunk rows (power of two, divides N)
  // per-row: 3 bf16 act buffers (3*2048 B) + 2 Pp f32 partial sets (2*256 B)
  while (CK > 256 && wbytes + (size_t)CK * 6656 > ws_size) CK >>= 1;
  bf16* actA = (bf16*)alloc((size_t)CK * 2048);          // h1
  bf16* actB = (bf16*)alloc((size_t)CK * 2048);          // gb
  bf16* actD = (bf16*)alloc((size_t)CK * 2048);          // f1 -> g1f (in place)
  float* Pp0 = (float*)alloc((size_t)CK * 4 * 16 * 4);   // gemm1 partials
  float* Pp1 = (float*)alloc((size_t)CK * 4 * 16 * 4);   // gemm2 partials

  prep<<<1024, 256, 0, stream>>>(W2, Wf2, W1, Wff, W2bf, W2Tbf, Wf2bf, W1n, Wffn);

  const dim3 ggrid(CK / 256, 4);
  for (long r0 = 0; r0 < N; r0 += CK) {
    k1<<<CK / 32, 256, 0, stream>>>(z, W1, b1, Wp, bp, Wf1, bf1, actA, actD, r0);
    gemm_k<0><<<ggrid, 512, 0, stream>>>(
        actA, W2bf, b2, Wh, nullptr, actD, actB, nullptr, nullptr, CK);
    gemm_k<1><<<ggrid, 512, 0, stream>>>(
        actB, W2Tbf, nullptr, nullptr, actA, nullptr, nullptr, W1n, Pp0, CK);
    gemm_k<2><<<ggrid, 512, 0, stream>>>(
        actD, Wf2bf, bf2, nullptr, actA, nullptr, nullptr, Wffn, Pp1, CK);
    k7<<<CK / 16, 256, 0, stream>>>(Pp0, Pp1, bff, out, r0, CK);
  }
}

// Round 20
// 341.459 us; speedup vs baseline: 1.0294x; 1.0294x over previous
//
#include <hip/hip_runtime.h>
#include <hip/hip_bf16.h>

typedef __hip_bfloat16 bf16;
typedef __attribute__((ext_vector_type(8))) short short8;
typedef __attribute__((ext_vector_type(4))) short s16x4;
typedef __attribute__((ext_vector_type(4))) float f32x4;

__device__ __forceinline__ float b2f(unsigned short u) {
  union { unsigned u; float f; } x; x.u = ((unsigned)u) << 16; return x.f;
}
__device__ __forceinline__ bf16 f2b(float f) { return __float2bfloat16(f); }
__device__ __forceinline__ short bfbits(float f) {
  union { float f; unsigned u; } x; x.f = f;
  unsigned r = x.u + 0x7fff + ((x.u >> 16) & 1);  // RNE
  return (short)(r >> 16);
}
// tanh(x) = sign(x) * (1-t)/(1+t), t = e^{-2|x|}  — ~8 VALU ops, err ~1e-6
__device__ __forceinline__ float tanh_fast(float x) {
  float t = __expf(-2.f * fabsf(x));
  float r = (1.f - t) * __builtin_amdgcn_rcpf(1.f + t);
  return copysignf(r, x);
}

#define GLOAD_LDS16(gp, lp) __builtin_amdgcn_global_load_lds( \
    (const __attribute__((address_space(1))) void*)(gp), \
    (__attribute__((address_space(3))) void*)(lp), 16, 0, 0)

// ---------------- prep: bf16 weight layouts (coalesced transpose) ----------
__global__ __launch_bounds__(256) void prep(
    const float* __restrict__ W2, const float* __restrict__ Wf2,
    const float* __restrict__ W1, const float* __restrict__ Wff,
    bf16* __restrict__ W2bf, bf16* __restrict__ W2Tbf,
    bf16* __restrict__ Wf2bf, bf16* __restrict__ W1n,
    bf16* __restrict__ Wffn)
{
  __shared__ float T[32][33];
  const int tid = threadIdx.x, bx = blockIdx.x;
  const int tx = bx & 31, ty = bx >> 5;
  const int r = tid >> 3, c4 = (tid & 7) * 4;
  const long ibase = (long)(ty * 32 + r) * 1024 + tx * 32 + c4;

  f32x4 v = *(const f32x4*)(W2 + ibase);
  f32x4 vf = *(const f32x4*)(Wf2 + ibase);
  s16x4 sv, sf;
  #pragma unroll
  for (int j = 0; j < 4; ++j) {
    sv[j] = bfbits(v[j]); sf[j] = bfbits(vf[j]);
    T[r][c4 + j] = v[j];
  }
  *(s16x4*)(W2bf + ibase) = sv;
  *(s16x4*)(Wf2bf + ibase) = sf;
  __syncthreads();
  const int oc = tid >> 3, or4 = (tid & 7) * 4;
  s16x4 st;
  #pragma unroll
  for (int j = 0; j < 4; ++j) st[j] = bfbits(T[or4 + j][oc]);
  *(s16x4*)(W2Tbf + (long)(tx * 32 + oc) * 1024 + ty * 32 + or4) = st;

  if (bx < 32) {  // W1n (16x1024, transpose of W1) + Wffn (straight)
    #pragma unroll
    for (int rep = 0; rep < 2; ++rep) {
      int i = bx * 512 + rep * 256 + tid;
      int rr = i >> 10, cc = i & 1023;
      W1n[i] = f2b(W1[cc * 16 + rr]);
      Wffn[i] = f2b(Wff[i]);
    }
  }
}

// ---------------- K1: h1 = tanh(z@W1^T+b1); f1 = [z,u]@Wf1^T+bf1 -----------
__global__ __launch_bounds__(256) void k1(
    const float* __restrict__ z, const float* __restrict__ W1,
    const float* __restrict__ b1, const float* __restrict__ Wp,
    const float* __restrict__ bp, const float* __restrict__ Wf1,
    const float* __restrict__ bf1v,
    bf16* __restrict__ h1, bf16* __restrict__ f1out, long grow0)
{
  __shared__ float zs[32][16];
  __shared__ float us[32][4];
  const int tid = threadIdx.x;
  const long r0 = (long)blockIdx.x * 32;
  for (int i = tid; i < 512; i += 256) {
    int r = i >> 4, c = i & 15;
    zs[r][c] = z[(grow0 + r0 + r) * 16 + c];
  }
  __syncthreads();
  if (tid < 128) {
    int r = tid >> 2, a = tid & 3;
    float acc = bp[a];
    #pragma unroll
    for (int k = 0; k < 16; ++k) acc = fmaf(zs[r][k], Wp[a * 16 + k], acc);
    us[r][a] = tanh_fast(acc);
  }
  __syncthreads();
  #pragma unroll
  for (int jj = 0; jj < 4; ++jj) {
    const int c = tid + jj * 256;
    {  // h1
      float w[16];
      #pragma unroll
      for (int k = 0; k < 16; ++k) w[k] = W1[c * 16 + k];
      const float bc = b1[c];
      for (int r = 0; r < 32; ++r) {
        float a = bc;
        #pragma unroll
        for (int k = 0; k < 16; ++k) a = fmaf(zs[r][k], w[k], a);
        h1[(r0 + r) * 1024 + c] = f2b(tanh_fast(a));
      }
    }
    {  // f1
      float wf[20];
      #pragma unroll
      for (int k = 0; k < 20; ++k) wf[k] = Wf1[c * 20 + k];
      const float bfc = bf1v[c];
      for (int r = 0; r < 32; ++r) {
        float f = bfc;
        #pragma unroll
        for (int k = 0; k < 16; ++k) f = fmaf(zs[r][k], wf[k], f);
        #pragma unroll
        for (int a = 0; a < 4; ++a) f = fmaf(us[r][a], wf[16 + a], f);
        f1out[(r0 + r) * 1024 + c] = f2b(f);
      }
    }
  }
}

// ---------------- MFMA GEMM 256x256, 8 waves, BK=64, 2-buf (R18 loop) ------
// EPI 0: x=a2. Pass 1: s1=1-tanh^2(x+b2) -> Ot (transpose via LDS, per col
//        half). Pass 2: row-major coalesced — ONE short8 f1 load + short8
//        stores of O1=g1f=tanh(f)+f*s1 and O2=gb=s1*Wh (Wh staged in LDS).
//        Replaces 64 scalar bf16 stores + 32 scalar loads per thread (R18:
//        writes at 1.17 TB/s, 4x32-B scattered segments per wave store).
// EPI 1/2: unchanged — g-tile -> Ot[256][136] two col-half phases, project
//        @Wn^T, write Pp partials.
template<int EPI>
__global__ __launch_bounds__(512, 2) void gemm_k(
    const bf16* __restrict__ A, const bf16* __restrict__ Bp,
    const float* __restrict__ bias, const float* __restrict__ Whv,
    const bf16* __restrict__ h1,
    bf16* O1, bf16* __restrict__ O2,   // O1 NOT restrict: in-place f1->g1f
    const bf16* __restrict__ Wn, float* __restrict__ Pp, int ckRows)
{
  __shared__ __align__(16) char smem[131072];  // As[2] @0, Bs[2] @65536
  const int tid = threadIdx.x;
  const int lane = tid & 63, wid = tid >> 6;
  const int wr = wid >> 2, wc = wid & 3;
  const int fr = lane & 15, kg = lane >> 4;
  const long row0 = (long)blockIdx.x * 256;
  const int col0 = blockIdx.y * 256;

  // staging: 512 thr x 8 elem = 64 rows x 64 k per gload round (gi=0..3)
  const int sr0 = tid >> 3;                               // row within round
  const int sk0 = ((tid >> 2) & 1) * 32 +
                  (((tid & 3) ^ ((tid >> 4) & 3))) * 8;   // swizzled k-chunk
  const int swr = (fr >> 1) & 3;                          // read-side XOR

  const bf16* gA0 = A + (row0 + sr0) * 1024 + sk0;
  const bf16* gB0 = Bp + ((long)col0 + sr0) * 1024 + sk0;
  const int rdA = (wr * 128 + fr) * 64 + (kg ^ swr) * 8;  // + m*1024 + kc*32
  const int rdB = (wc * 64 + fr) * 64 + (kg ^ swr) * 8;   // + n*1024 + kc*32

  f32x4 acc[8][4] = {};

  auto stage = [&](int b, int k0) {
    bf16* as = (bf16*)smem + b * 16384;           // 32 KB per A buf
    bf16* bs = (bf16*)smem + 32768 + b * 16384;   // Bs base at byte 65536
    #pragma unroll
    for (int gi = 0; gi < 4; ++gi)
      GLOAD_LDS16(gA0 + gi * 65536 + k0, as + gi * 4096 + tid * 8);
    #pragma unroll
    for (int gi = 0; gi < 4; ++gi)
      GLOAD_LDS16(gB0 + gi * 65536 + k0, bs + gi * 4096 + tid * 8);
  };

  stage(0, 0);
  __syncthreads();

  #pragma unroll 2
  for (int kt = 0; kt < 16; ++kt) {
    const int cur = kt & 1;                 // static under unroll-2
    if (kt < 15) stage(cur ^ 1, (kt + 1) * 64);
    const bf16* as = (const bf16*)smem + cur * 16384;
    const bf16* bs = (const bf16*)smem + 32768 + cur * 16384;
    #pragma unroll
    for (int kc = 0; kc < 2; ++kc) {
      short8 af[8], bfr[4];
      #pragma unroll
      for (int m = 0; m < 8; ++m)
        af[m] = *(const short8*)(as + rdA + m * 1024 + kc * 32);
      #pragma unroll
      for (int n = 0; n < 4; ++n)
        bfr[n] = *(const short8*)(bs + rdB + n * 1024 + kc * 32);
      __builtin_amdgcn_s_setprio(1);
      #pragma unroll
      for (int m = 0; m < 8; ++m)
        #pragma unroll
        for (int n = 0; n < 4; ++n)
          acc[m][n] = __builtin_amdgcn_mfma_f32_16x16x32_bf16(af[m], bfr[n], acc[m][n], 0, 0, 0);
      __builtin_amdgcn_s_setprio(0);
    }
    __syncthreads();  // drains vmcnt+lgkm: prefetch landed, reads done
  }

  if (EPI == 0) {
    bf16* Ot = (bf16*)smem;                  // [256][136] — one col-half
    float* Whs = (float*)(smem + 69632);     // [256]
    if (tid < 256) Whs[tid] = Whv[col0 + tid];
    const bf16* F1 = (const bf16*)O1;        // f1, in place
    #pragma unroll
    for (int ph = 0; ph < 2; ++ph) {
      if ((wc >> 1) == ph) {  // this wave's 64 cols live in half ph
        #pragma unroll
        for (int m = 0; m < 8; ++m) {
          const int rl0 = wr * 128 + m * 16 + kg * 4;
          #pragma unroll
          for (int n = 0; n < 4; ++n) {
            const int cl = (wc & 1) * 64 + n * 16 + fr;   // 0..127
            const float b2c = bias[col0 + ph * 128 + cl];
            f32x4 v = acc[m][n];
            #pragma unroll
            for (int j = 0; j < 4; ++j) {
              float h = tanh_fast(v[j] + b2c);
              Ot[(rl0 + j) * 136 + cl] = f2b(1.f - h * h);  // s1
            }
          }
        }
      }
      __syncthreads();  // s1 half staged (+Whs on ph=0)
      const int c8 = tid & 15, rb = tid >> 4;  // 16 chunks/row, 32 rows/pass
      #pragma unroll
      for (int pass = 0; pass < 8; ++pass) {
        const int row = pass * 32 + rb;
        const long gidx = (row0 + row) * 1024 + col0 + ph * 128 + c8 * 8;
        short8 s8 = *(const short8*)(Ot + row * 136 + c8 * 8);
        short8 f8 = *(const short8*)(F1 + gidx);
        short8 o1v, o2v;
        #pragma unroll
        for (int e = 0; e < 8; ++e) {
          float s1 = b2f((unsigned short)s8[e]);
          float f  = b2f((unsigned short)f8[e]);
          o1v[e] = bfbits(tanh_fast(f) + f * s1);
          o2v[e] = bfbits(s1 * Whs[ph * 128 + c8 * 8 + e]);
        }
        *(short8*)(O1 + gidx) = o1v;
        *(short8*)(O2 + gidx) = o2v;
      }
      if (ph == 0) __syncthreads();  // reads done before half 1 overwrites
    }
  } else {
    bf16* Ot = (bf16*)smem;  // [256][136] bf16 — holds ONE column half
    f32x4 pacc[2] = {};
    #pragma unroll
    for (int ph = 0; ph < 2; ++ph) {
      if ((wc >> 1) == ph) {  // this wave's 64 cols live in half ph
        #pragma unroll
        for (int m = 0; m < 8; ++m) {
          const int rl0 = wr * 128 + m * 16 + kg * 4;
          const long gr0 = row0 + rl0;
          #pragma unroll
          for (int n = 0; n < 4; ++n) {
            const int cl = (wc & 1) * 64 + n * 16 + fr;       // 0..127
            const int gc = col0 + ph * 128 + cl;
            f32x4 v = acc[m][n];
            #pragma unroll
            for (int j = 0; j < 4; ++j) {
              const long idx = (gr0 + j) * 1024 + gc;
              float x = v[j], g;
              if (EPI == 1) {
                float hh = __bfloat162float(h1[idx]);
                g = x * (1.f - hh * hh);
              } else {
                float f = x + bias[gc];
                float hh = __bfloat162float(h1[idx]);
                g = tanh_fast(f) + f * (1.f - hh * hh);
              }
              Ot[(rl0 + j) * 136 + cl] = f2b(g);
            }
          }
        }
      }
      __syncthreads();  // half-tile staged
      #pragma unroll
      for (int sub = 0; sub < 2; ++sub) {
        const int rl0 = wid * 32 + sub * 16;
        #pragma unroll
        for (int ks = 0; ks < 4; ++ks) {
          short8 afrag = *(const short8*)(Ot + (rl0 + fr) * 136 + ks * 32 + kg * 8);
          short8 bfrag = *(const short8*)(Wn + fr * 1024 + col0 + ph * 128 + ks * 32 + kg * 8);
          pacc[sub] = __builtin_amdgcn_mfma_f32_16x16x32_bf16(afrag, bfrag, pacc[sub], 0, 0, 0);
        }
      }
      if (ph == 0) __syncthreads();  // reads done before half 1 overwrites
    }
    #pragma unroll
    for (int sub = 0; sub < 2; ++sub) {
      const int rl0 = wid * 32 + sub * 16;
      #pragma unroll
      for (int j = 0; j < 4; ++j)
        Pp[(((long)blockIdx.y) * ckRows + row0 + rl0 + kg * 4 + j) * 16 + fr] = pacc[sub][j];
    }
  }
}

// ---------------- k7: out = J*(sum_cb(Pp0+Pp1) + bff) ----------------------
__global__ __launch_bounds__(256) void k7(
    const float* __restrict__ Pp0, const float* __restrict__ Pp1,
    const float* __restrict__ bff, float* __restrict__ out,
    long grow0, int ckRows)
{
  int i = blockIdx.x * 256 + threadIdx.x;
  int r = i >> 4, j = i & 15, jp = (j + 8) & 15;
  float s = bff[jp];
  #pragma unroll
  for (int cb = 0; cb < 4; ++cb) {
    long o = ((long)cb * ckRows + r) * 16 + jp;
    s += Pp0[o] + Pp1[o];
  }
  out[(grow0 + r) * 16 + j] = (j < 8) ? s : -s;
}

// ---------------- host ----------------
extern "C" void kernel_launch(void* const* d_in, const int* in_sizes, int n_in,
                              void* d_out, int out_size, void* d_ws, size_t ws_size,
                              hipStream_t stream) {
  const float* z   = (const float*)d_in[1];
  const float* W1  = (const float*)d_in[2];
  const float* b1  = (const float*)d_in[3];
  const float* W2  = (const float*)d_in[4];
  const float* b2  = (const float*)d_in[5];
  const float* Wh  = (const float*)d_in[6];
  const float* Wf1 = (const float*)d_in[8];
  const float* bf1 = (const float*)d_in[9];
  const float* Wf2 = (const float*)d_in[10];
  const float* bf2 = (const float*)d_in[11];
  const float* Wff = (const float*)d_in[12];
  const float* bff = (const float*)d_in[13];
  const float* Wp  = (const float*)d_in[14];
  const float* bp  = (const float*)d_in[15];
  float* out = (float*)d_out;
  const int N = in_sizes[1] / 16;

  char* p = (char*)d_ws;
  auto alloc = [&](size_t bytes) {
    char* q = p; p += (bytes + 255) & ~(size_t)255; return q;
  };
  bf16* W2bf  = (bf16*)alloc(1024 * 1024 * 2);
  bf16* W2Tbf = (bf16*)alloc(1024 * 1024 * 2);
  bf16* Wf2bf = (bf16*)alloc(1024 * 1024 * 2);
  bf16* W1n   = (bf16*)alloc(16 * 1024 * 2);
  bf16* Wffn  = (bf16*)alloc(16 * 1024 * 2);
  size_t wbytes = (size_t)(p - (char*)d_ws);

  int CK = N;  // chunk rows (power of two, divides N)
  // per-row: 3 bf16 act buffers (3*2048 B) + 2 Pp f32 partial sets (2*256 B)
  while (CK > 256 && wbytes + (size_t)CK * 6656 > ws_size) CK >>= 1;
  bf16* actA = (bf16*)alloc((size_t)CK * 2048);          // h1
  bf16* actB = (bf16*)alloc((size_t)CK * 2048);          // gb
  bf16* actD = (bf16*)alloc((size_t)CK * 2048);          // f1 -> g1f (in place)
  float* Pp0 = (float*)alloc((size_t)CK * 4 * 16 * 4);   // gemm1 partials
  float* Pp1 = (float*)alloc((size_t)CK * 4 * 16 * 4);   // gemm2 partials

  prep<<<1024, 256, 0, stream>>>(W2, Wf2, W1, Wff, W2bf, W2Tbf, Wf2bf, W1n, Wffn);

  const dim3 ggrid(CK / 256, 4);
  for (long r0 = 0; r0 < N; r0 += CK) {
    k1<<<CK / 32, 256, 0, stream>>>(z, W1, b1, Wp, bp, Wf1, bf1, actA, actD, r0);
    gemm_k<0><<<ggrid, 512, 0, stream>>>(
        actA, W2bf, b2, Wh, nullptr, actD, actB, nullptr, nullptr, CK);
    gemm_k<1><<<ggrid, 512, 0, stream>>>(
        actB, W2Tbf, nullptr, nullptr, actA, nullptr, nullptr, W1n, Pp0, CK);
    gemm_k<2><<<ggrid, 512, 0, stream>>>(
        actD, Wf2bf, bf2, nullptr, actA, nullptr, nullptr, Wffn, Pp1, CK);
    k7<<<CK / 16, 256, 0, stream>>>(Pp0, Pp1, bff, out, r0, CK);
  }
}

// Round 21
// 337.587 us; speedup vs baseline: 1.0412x; 1.0115x over previous
//
#include <hip/hip_runtime.h>
#include <hip/hip_bf16.h>

typedef __hip_bfloat16 bf16;
typedef __attribute__((ext_vector_type(8))) short short8;
typedef __attribute__((ext_vector_type(4))) short s16x4;
typedef __attribute__((ext_vector_type(4))) float f32x4;

__device__ __forceinline__ bf16 f2b(float f) { return __float2bfloat16(f); }
__device__ __forceinline__ short bfbits(float f) {
  union { float f; unsigned u; } x; x.f = f;
  unsigned r = x.u + 0x7fff + ((x.u >> 16) & 1);  // RNE
  return (short)(r >> 16);
}
// tanh(x) = sign(x) * (1-t)/(1+t), t = e^{-2|x|}  — ~8 VALU ops, err ~1e-6
__device__ __forceinline__ float tanh_fast(float x) {
  float t = __expf(-2.f * fabsf(x));
  float r = (1.f - t) * __builtin_amdgcn_rcpf(1.f + t);
  return copysignf(r, x);
}

#define GLOAD_LDS16(gp, lp) __builtin_amdgcn_global_load_lds( \
    (const __attribute__((address_space(1))) void*)(gp), \
    (__attribute__((address_space(3))) void*)(lp), 16, 0, 0)

// ---------------- prep: bf16 weight layouts (coalesced transpose) ----------
__global__ __launch_bounds__(256) void prep(
    const float* __restrict__ W2, const float* __restrict__ Wf2,
    const float* __restrict__ W1, const float* __restrict__ Wff,
    bf16* __restrict__ W2bf, bf16* __restrict__ W2Tbf,
    bf16* __restrict__ Wf2bf, bf16* __restrict__ W1n,
    bf16* __restrict__ Wffn)
{
  __shared__ float T[32][33];
  const int tid = threadIdx.x, bx = blockIdx.x;
  const int tx = bx & 31, ty = bx >> 5;
  const int r = tid >> 3, c4 = (tid & 7) * 4;
  const long ibase = (long)(ty * 32 + r) * 1024 + tx * 32 + c4;

  f32x4 v = *(const f32x4*)(W2 + ibase);
  f32x4 vf = *(const f32x4*)(Wf2 + ibase);
  s16x4 sv, sf;
  #pragma unroll
  for (int j = 0; j < 4; ++j) {
    sv[j] = bfbits(v[j]); sf[j] = bfbits(vf[j]);
    T[r][c4 + j] = v[j];
  }
  *(s16x4*)(W2bf + ibase) = sv;
  *(s16x4*)(Wf2bf + ibase) = sf;
  __syncthreads();
  const int oc = tid >> 3, or4 = (tid & 7) * 4;
  s16x4 st;
  #pragma unroll
  for (int j = 0; j < 4; ++j) st[j] = bfbits(T[or4 + j][oc]);
  *(s16x4*)(W2Tbf + (long)(tx * 32 + oc) * 1024 + ty * 32 + or4) = st;

  if (bx < 32) {  // W1n (16x1024, transpose of W1) + Wffn (straight)
    #pragma unroll
    for (int rep = 0; rep < 2; ++rep) {
      int i = bx * 512 + rep * 256 + tid;
      int rr = i >> 10, cc = i & 1023;
      W1n[i] = f2b(W1[cc * 16 + rr]);
      Wffn[i] = f2b(Wff[i]);
    }
  }
}

// ---------------- K1: h1 = tanh(z@W1^T+b1); f1 = [z,u]@Wf1^T+bf1 -----------
__global__ __launch_bounds__(256) void k1(
    const float* __restrict__ z, const float* __restrict__ W1,
    const float* __restrict__ b1, const float* __restrict__ Wp,
    const float* __restrict__ bp, const float* __restrict__ Wf1,
    const float* __restrict__ bf1v,
    bf16* __restrict__ h1, bf16* __restrict__ f1out, long grow0)
{
  __shared__ float zs[32][16];
  __shared__ float us[32][4];
  const int tid = threadIdx.x;
  const long r0 = (long)blockIdx.x * 32;
  for (int i = tid; i < 512; i += 256) {
    int r = i >> 4, c = i & 15;
    zs[r][c] = z[(grow0 + r0 + r) * 16 + c];
  }
  __syncthreads();
  if (tid < 128) {
    int r = tid >> 2, a = tid & 3;
    float acc = bp[a];
    #pragma unroll
    for (int k = 0; k < 16; ++k) acc = fmaf(zs[r][k], Wp[a * 16 + k], acc);
    us[r][a] = tanh_fast(acc);
  }
  __syncthreads();
  #pragma unroll
  for (int jj = 0; jj < 4; ++jj) {
    const int c = tid + jj * 256;
    {  // h1
      float w[16];
      #pragma unroll
      for (int k = 0; k < 16; ++k) w[k] = W1[c * 16 + k];
      const float bc = b1[c];
      for (int r = 0; r < 32; ++r) {
        float a = bc;
        #pragma unroll
        for (int k = 0; k < 16; ++k) a = fmaf(zs[r][k], w[k], a);
        h1[(r0 + r) * 1024 + c] = f2b(tanh_fast(a));
      }
    }
    {  // f1
      float wf[20];
      #pragma unroll
      for (int k = 0; k < 20; ++k) wf[k] = Wf1[c * 20 + k];
      const float bfc = bf1v[c];
      for (int r = 0; r < 32; ++r) {
        float f = bfc;
        #pragma unroll
        for (int k = 0; k < 16; ++k) f = fmaf(zs[r][k], wf[k], f);
        #pragma unroll
        for (int a = 0; a < 4; ++a) f = fmaf(us[r][a], wf[16 + a], f);
        f1out[(r0 + r) * 1024 + c] = f2b(f);
      }
    }
  }
}

// ---------------- MFMA GEMM 256x256, 8 waves, BK=64, 2-buf ----------------
// Session-best configuration (R18, 340.3 µs): 16 K-steps, 64 MFMA/wave per
// barrier window, 2-buf stage->compute->__syncthreads semantics.
// LDS: As[2] @0 (2x32KB), Bs[2] @65536 (2x32KB) = 128 KB, 1 block/CU.
// Swizzle: chunk XOR within each 32-k half of the 64-k row.
// EPI 0: x=a2. h2=tanh(x+b2); s1=1-h2^2; O2=gb=s1*Wh[c];
//        f=O1[idx] (=f1 precomputed); O1=g1f=tanh(f)+f*s1 IN PLACE.
// EPI 1/2: g-tile -> Ot[256][136] in two column-half phases, project @Wn^T,
//          write Pp partials (per col-block).
template<int EPI>
__global__ __launch_bounds__(512, 2) void gemm_k(
    const bf16* __restrict__ A, const bf16* __restrict__ Bp,
    const float* __restrict__ bias, const float* __restrict__ Whv,
    const bf16* __restrict__ h1,
    bf16* O1, bf16* __restrict__ O2,   // O1 NOT restrict: in-place f1->g1f
    const bf16* __restrict__ Wn, float* __restrict__ Pp, int ckRows)
{
  __shared__ __align__(16) char smem[131072];  // As[2] @0, Bs[2] @65536
  const int tid = threadIdx.x;
  const int lane = tid & 63, wid = tid >> 6;
  const int wr = wid >> 2, wc = wid & 3;
  const int fr = lane & 15, kg = lane >> 4;
  const long row0 = (long)blockIdx.x * 256;
  const int col0 = blockIdx.y * 256;

  // staging: 512 thr x 8 elem = 64 rows x 64 k per gload round (gi=0..3)
  const int sr0 = tid >> 3;                               // row within round
  const int sk0 = ((tid >> 2) & 1) * 32 +
                  (((tid & 3) ^ ((tid >> 4) & 3))) * 8;   // swizzled k-chunk
  const int swr = (fr >> 1) & 3;                          // read-side XOR

  const bf16* gA0 = A + (row0 + sr0) * 1024 + sk0;
  const bf16* gB0 = Bp + ((long)col0 + sr0) * 1024 + sk0;
  const int rdA = (wr * 128 + fr) * 64 + (kg ^ swr) * 8;  // + m*1024 + kc*32
  const int rdB = (wc * 64 + fr) * 64 + (kg ^ swr) * 8;   // + n*1024 + kc*32

  f32x4 acc[8][4] = {};

  auto stage = [&](int b, int k0) {
    bf16* as = (bf16*)smem + b * 16384;           // 32 KB per A buf
    bf16* bs = (bf16*)smem + 32768 + b * 16384;   // Bs base at byte 65536
    #pragma unroll
    for (int gi = 0; gi < 4; ++gi)
      GLOAD_LDS16(gA0 + gi * 65536 + k0, as + gi * 4096 + tid * 8);
    #pragma unroll
    for (int gi = 0; gi < 4; ++gi)
      GLOAD_LDS16(gB0 + gi * 65536 + k0, bs + gi * 4096 + tid * 8);
  };

  stage(0, 0);
  __syncthreads();

  #pragma unroll 2
  for (int kt = 0; kt < 16; ++kt) {
    const int cur = kt & 1;                 // static under unroll-2
    if (kt < 15) stage(cur ^ 1, (kt + 1) * 64);
    const bf16* as = (const bf16*)smem + cur * 16384;
    const bf16* bs = (const bf16*)smem + 32768 + cur * 16384;
    #pragma unroll
    for (int kc = 0; kc < 2; ++kc) {
      short8 af[8], bfr[4];
      #pragma unroll
      for (int m = 0; m < 8; ++m)
        af[m] = *(const short8*)(as + rdA + m * 1024 + kc * 32);
      #pragma unroll
      for (int n = 0; n < 4; ++n)
        bfr[n] = *(const short8*)(bs + rdB + n * 1024 + kc * 32);
      __builtin_amdgcn_s_setprio(1);
      #pragma unroll
      for (int m = 0; m < 8; ++m)
        #pragma unroll
        for (int n = 0; n < 4; ++n)
          acc[m][n] = __builtin_amdgcn_mfma_f32_16x16x32_bf16(af[m], bfr[n], acc[m][n], 0, 0, 0);
      __builtin_amdgcn_s_setprio(0);
    }
    __syncthreads();  // drains vmcnt+lgkm: prefetch landed, reads done
  }

  if (EPI == 0) {
    #pragma unroll
    for (int m = 0; m < 8; ++m) {
      const long gr0 = row0 + wr * 128 + m * 16 + kg * 4;
      #pragma unroll
      for (int n = 0; n < 4; ++n) {
        const int gc = col0 + wc * 64 + n * 16 + fr;
        const float b2c = bias[gc], whc = Whv[gc];
        f32x4 v = acc[m][n];
        #pragma unroll
        for (int j = 0; j < 4; ++j) {
          const long idx = (gr0 + j) * 1024 + gc;
          float h = tanh_fast(v[j] + b2c);
          float s1v = 1.f - h * h;
          float f = __bfloat162float(((const bf16*)O1)[idx]);  // f1 in place
          O2[idx] = f2b(s1v * whc);
          O1[idx] = f2b(tanh_fast(f) + f * s1v);
        }
      }
    }
  } else {
    bf16* Ot = (bf16*)smem;  // [256][136] bf16 — holds ONE column half
    f32x4 pacc[2] = {};
    #pragma unroll
    for (int ph = 0; ph < 2; ++ph) {
      if ((wc >> 1) == ph) {  // this wave's 64 cols live in half ph
        #pragma unroll
        for (int m = 0; m < 8; ++m) {
          const int rl0 = wr * 128 + m * 16 + kg * 4;
          const long gr0 = row0 + rl0;
          #pragma unroll
          for (int n = 0; n < 4; ++n) {
            const int cl = (wc & 1) * 64 + n * 16 + fr;       // 0..127
            const int gc = col0 + ph * 128 + cl;
            f32x4 v = acc[m][n];
            #pragma unroll
            for (int j = 0; j < 4; ++j) {
              const long idx = (gr0 + j) * 1024 + gc;
              float x = v[j], g;
              if (EPI == 1) {
                float hh = __bfloat162float(h1[idx]);
                g = x * (1.f - hh * hh);
              } else {
                float f = x + bias[gc];
                float hh = __bfloat162float(h1[idx]);
                g = tanh_fast(f) + f * (1.f - hh * hh);
              }
              Ot[(rl0 + j) * 136 + cl] = f2b(g);
            }
          }
        }
      }
      __syncthreads();  // half-tile staged
      #pragma unroll
      for (int sub = 0; sub < 2; ++sub) {
        const int rl0 = wid * 32 + sub * 16;
        #pragma unroll
        for (int ks = 0; ks < 4; ++ks) {
          short8 afrag = *(const short8*)(Ot + (rl0 + fr) * 136 + ks * 32 + kg * 8);
          short8 bfrag = *(const short8*)(Wn + fr * 1024 + col0 + ph * 128 + ks * 32 + kg * 8);
          pacc[sub] = __builtin_amdgcn_mfma_f32_16x16x32_bf16(afrag, bfrag, pacc[sub], 0, 0, 0);
        }
      }
      if (ph == 0) __syncthreads();  // reads done before half 1 overwrites
    }
    #pragma unroll
    for (int sub = 0; sub < 2; ++sub) {
      const int rl0 = wid * 32 + sub * 16;
      #pragma unroll
      for (int j = 0; j < 4; ++j)
        Pp[(((long)blockIdx.y) * ckRows + row0 + rl0 + kg * 4 + j) * 16 + fr] = pacc[sub][j];
    }
  }
}

// ---------------- k7: out = J*(sum_cb(Pp0+Pp1) + bff) ----------------------
__global__ __launch_bounds__(256) void k7(
    const float* __restrict__ Pp0, const float* __restrict__ Pp1,
    const float* __restrict__ bff, float* __restrict__ out,
    long grow0, int ckRows)
{
  int i = blockIdx.x * 256 + threadIdx.x;
  int r = i >> 4, j = i & 15, jp = (j + 8) & 15;
  float s = bff[jp];
  #pragma unroll
  for (int cb = 0; cb < 4; ++cb) {
    long o = ((long)cb * ckRows + r) * 16 + jp;
    s += Pp0[o] + Pp1[o];
  }
  out[(grow0 + r) * 16 + j] = (j < 8) ? s : -s;
}

// ---------------- host ----------------
extern "C" void kernel_launch(void* const* d_in, const int* in_sizes, int n_in,
                              void* d_out, int out_size, void* d_ws, size_t ws_size,
                              hipStream_t stream) {
  const float* z   = (const float*)d_in[1];
  const float* W1  = (const float*)d_in[2];
  const float* b1  = (const float*)d_in[3];
  const float* W2  = (const float*)d_in[4];
  const float* b2  = (const float*)d_in[5];
  const float* Wh  = (const float*)d_in[6];
  const float* Wf1 = (const float*)d_in[8];
  const float* bf1 = (const float*)d_in[9];
  const float* Wf2 = (const float*)d_in[10];
  const float* bf2 = (const float*)d_in[11];
  const float* Wff = (const float*)d_in[12];
  const float* bff = (const float*)d_in[13];
  const float* Wp  = (const float*)d_in[14];
  const float* bp  = (const float*)d_in[15];
  float* out = (float*)d_out;
  const int N = in_sizes[1] / 16;

  char* p = (char*)d_ws;
  auto alloc = [&](size_t bytes) {
    char* q = p; p += (bytes + 255) & ~(size_t)255; return q;
  };
  bf16* W2bf  = (bf16*)alloc(1024 * 1024 * 2);
  bf16* W2Tbf = (bf16*)alloc(1024 * 1024 * 2);
  bf16* Wf2bf = (bf16*)alloc(1024 * 1024 * 2);
  bf16* W1n   = (bf16*)alloc(16 * 1024 * 2);
  bf16* Wffn  = (bf16*)alloc(16 * 1024 * 2);
  size_t wbytes = (size_t)(p - (char*)d_ws);

  int CK = N;  // chunk rows (power of two, divides N)
  // per-row: 3 bf16 act buffers (3*2048 B) + 2 Pp f32 partial sets (2*256 B)
  while (CK > 256 && wbytes + (size_t)CK * 6656 > ws_size) CK >>= 1;
  bf16* actA = (bf16*)alloc((size_t)CK * 2048);          // h1
  bf16* actB = (bf16*)alloc((size_t)CK * 2048);          // gb
  bf16* actD = (bf16*)alloc((size_t)CK * 2048);          // f1 -> g1f (in place)
  float* Pp0 = (float*)alloc((size_t)CK * 4 * 16 * 4);   // gemm1 partials
  float* Pp1 = (float*)alloc((size_t)CK * 4 * 16 * 4);   // gemm2 partials

  prep<<<1024, 256, 0, stream>>>(W2, Wf2, W1, Wff, W2bf, W2Tbf, Wf2bf, W1n, Wffn);

  const dim3 ggrid(CK / 256, 4);
  for (long r0 = 0; r0 < N; r0 += CK) {
    k1<<<CK / 32, 256, 0, stream>>>(z, W1, b1, Wp, bp, Wf1, bf1, actA, actD, r0);
    gemm_k<0><<<ggrid, 512, 0, stream>>>(
        actA, W2bf, b2, Wh, nullptr, actD, actB, nullptr, nullptr, CK);
    gemm_k<1><<<ggrid, 512, 0, stream>>>(
        actB, W2Tbf, nullptr, nullptr, actA, nullptr, nullptr, W1n, Pp0, CK);
    gemm_k<2><<<ggrid, 512, 0, stream>>>(
        actD, Wf2bf, bf2, nullptr, actA, nullptr, nullptr, Wffn, Pp1, CK);
    k7<<<CK / 16, 256, 0, stream>>>(Pp0, Pp1, bff, out, r0, CK);
  }
}